// Round 10
// baseline (207.940 us; speedup 1.0000x reference)
//
#include <hip/hip_runtime.h>

// SparseAttention: B=8, M=N=4096, K=64, R=128 nnz/row (uniform CSR, sorted).
// Law (fits R2-R10): random 128B-line reads from L2 sustain ~0.25 lines/cy/CU
// (vs ~1-2 streamed) -> gather floor = bytes/16B / 2addr/cy = 54.6us. Measured
// 53-55 across every gather variant; invariant to MLP/occupancy/sched.
// R11: LDS column-sweep v2 (R9 retry, all 4 failures fixed):
//   (1) [d][col^d] XOR-swizzled LDS layout -> conflict-free reads AND writes
//       (R9's stride-144 was 8-way on every read: 5.3M conflict cycles),
//   (2) Tc=128 -> 64KB LDS -> 2 blocks/CU (16 waves, was 8),
//   (3) 1 row per 8-lane group (was 2 serial),
//   (4) T14 async staging: issue loads -> process tile -> write LDS -> barrier.
// Streams K/V from L2 (fast path), serves random edge reads from LDS.
#define Bc 8
#define Mc 4096
#define Nc 4096
#define Kc 64
#define Rc 128
#define Tc 128
#define NTl (Nc / Tc)   // 32 tiles

typedef _Float16 h16;
typedef h16 h16x2 __attribute__((ext_vector_type(2)));
typedef h16 h16x4 __attribute__((ext_vector_type(4)));
typedef h16 h16x8 __attribute__((ext_vector_type(8)));
typedef float f32x4 __attribute__((ext_vector_type(4)));

// DPP cross-lane reduce (validated R7/R8): xor1=0xB1, xor2=0x4E,
// row_half_mirror=0x141 (== xor4 once quads uniform) -> 8-lane group sum.
template<int CTRL>
__device__ __forceinline__ float dpp_badd(float x) {
    union { float f; int i; } u, r;
    u.f = x;
    r.i = __builtin_amdgcn_update_dpp(0, u.i, CTRL, 0xF, 0xF, true);
    return x + r.f;
}

// fp32 -> fp16 staging for K, V, Q.  XCD-aware: batch b converted by blocks
// with blockIdx&7 == b (same XCD the sweep blocks for batch b run on).
__global__ __launch_bounds__(256) void cvt_fp16(
    const f32x4* __restrict__ K4, const f32x4* __restrict__ V4,
    const f32x4* __restrict__ Q4,
    h16x4* __restrict__ Kh4, h16x4* __restrict__ Vh4, h16x4* __restrict__ Qh4)
{
    const int nb4   = Nc * Kc / 4;
    const int b     = blockIdx.x & 7;
    const int chunk = blockIdx.x >> 3;
    const int tsel  = chunk >> 8;           // 0:K 1:V 2:Q
    const int idx   = b * nb4 + ((chunk & 255) << 8) + threadIdx.x;
    const f32x4* src = (tsel == 0) ? K4 : (tsel == 1) ? V4 : Q4;
    h16x4*       dst = (tsel == 0) ? Kh4 : (tsel == 1) ? Vh4 : Qh4;
    f32x4 v = __builtin_nontemporal_load(&src[idx]);
    h16x4 o = { (h16)v.x, (h16)v.y, (h16)v.z, (h16)v.w };
    dst[idx] = o;
}

__global__ __launch_bounds__(512, 4) void sattn_sweep2(
    const int* __restrict__ cols,    // [M*R], sorted within row
    const h16* __restrict__ Qh,      // [B,M,K] fp16 (staged)
    const h16* __restrict__ Kh,      // [B,N,K] fp16 (staged)
    const h16* __restrict__ Vh,      // [B,N,K] fp16 (staged)
    float* __restrict__ out)         // [B,M,K] fp32
{
    const int b     = blockIdx.x & 7;        // XCD swizzle: one batch per XCD
    const int rblk  = blockIdx.x >> 3;       // 0..63 row-block within batch
    const int tid   = threadIdx.x;           // 0..511 (8 waves)
    const int ln    = tid & 7;               // lane in group; dims ln*8..ln*8+7
    const int gg    = tid >> 3;              // group 0..63: one row each
    const int gbase = (tid & 63) & 56;       // group's lane0 within wave
    const int row   = rblk * 64 + gg;

    // [buf][tensor K/V][d 0..7][col^d 0..127][8 h16] = 64 KB
    __shared__ __align__(16) h16 smem[2][2][8][Tc][8];

    const h16* Kb = Kh + ((size_t)b * Nc) * Kc;
    const h16* Vb = Vh + ((size_t)b * Nc) * Kc;

    // Q fragment: dims ln*8..ln*8+7 (group-shared row -> L1 broadcast).
    h16x8 qv = *(const h16x8*)(Qh + (((size_t)b * Mc + row) << 6) + ln * 8);
    h16x2 qh[4];
    #pragma unroll
    for (int j = 0; j < 4; ++j) qh[j] = h16x2{ qv[2 * j], qv[2 * j + 1] };

    const int* crow = cols + row * Rc;

    int   ptr = 0;
    float m = -1e30f, s = 0.f;
    float acc8[8] = {0.f,0.f,0.f,0.f,0.f,0.f,0.f,0.f};

    // ---- prologue: stage tile 0 (coalesced d-fast; swizzled dst) ----
    #pragma unroll
    for (int i = 0; i < 4; ++i) {
        int p = i * 512 + tid;               // 0..2047 pieces of 16B
        int tn = p >> 10, q = p & 1023, col = q >> 3, d = q & 7;
        const h16* src = (tn ? Vb : Kb) + (size_t)col * 64 + d * 8;
        *(h16x8*)&smem[0][tn][d][col ^ d][0] = *(const h16x8*)src;
    }
    __syncthreads();

    for (int t = 0; t < NTl; ++t) {
        const int cur = t & 1;

        // 1. issue next tile's loads into registers (latency hides under DS work)
        h16x8 stg[4];
        if (t + 1 < NTl) {
            #pragma unroll
            for (int i = 0; i < 4; ++i) {
                int p = i * 512 + tid;
                int tn = p >> 10, q = p & 1023, col = q >> 3, d = q & 7;
                const h16* src = (tn ? Vb : Kb)
                               + (size_t)((t + 1) * Tc + col) * 64 + d * 8;
                stg[i] = *(const h16x8*)src;
            }
        }

        // 2. process tile t: this group's edges with col in [t*Tc, (t+1)*Tc)
        const int c_end = (t + 1) * Tc;
        for (;;) {
            int idx = ptr + ln;
            int cv  = crow[idx < Rc ? idx : Rc - 1];
            bool valid = (idx < Rc) && (cv < c_end);
            unsigned long long bal = __ballot(valid);
            int n = __popcll((bal >> gbase) & 0xFFull);   // group-uniform
            if (n == 0) break;

            float lg[8]; int cl[8];
            #pragma unroll
            for (int j = 0; j < 8; ++j) if (j < n) {
                int c = __shfl(cv, gbase + j, 64) - t * Tc;   // tile-local col
                cl[j] = c;
                h16x8 kf = *(const h16x8*)&smem[cur][0][ln][c ^ ln][0];
                float a = 0.f;
                #pragma unroll
                for (int d2 = 0; d2 < 4; ++d2) {
                    h16x2 kj = { kf[2 * d2], kf[2 * d2 + 1] };
#if defined(__has_builtin)
#if __has_builtin(__builtin_amdgcn_fdot2)
                    a = __builtin_amdgcn_fdot2(qh[d2], kj, a, false);
#else
                    a += (float)qh[d2].x * (float)kj.x + (float)qh[d2].y * (float)kj.y;
#endif
#else
                    a += (float)qh[d2].x * (float)kj.x + (float)qh[d2].y * (float)kj.y;
#endif
                }
                a = dpp_badd<0xB1>(a);
                a = dpp_badd<0x4E>(a);
                a = dpp_badd<0x141>(a);
                lg[j] = a;                    // group-uniform logit
            }

            // online softmax: one rescale per chunk
            float cm = -1e30f;
            #pragma unroll
            for (int j = 0; j < 8; ++j) if (j < n) cm = fmaxf(cm, lg[j]);
            if (cm > m) {
                float sc = __expf(m - cm);
                s *= sc;
                #pragma unroll
                for (int d2 = 0; d2 < 8; ++d2) acc8[d2] *= sc;
                m = cm;
            }
            #pragma unroll
            for (int j = 0; j < 8; ++j) if (j < n) {
                float wj = __expf(lg[j] - m);
                s += wj;
                h16x8 vf = *(const h16x8*)&smem[cur][1][ln][cl[j] ^ ln][0];
                #pragma unroll
                for (int d2 = 0; d2 < 8; ++d2)
                    acc8[d2] = fmaf((float)vf[d2], wj, acc8[d2]);
            }
            ptr += n;
            if (n < 8) break;                 // sorted -> tile exhausted
        }

        // 3. publish staged tile into the other buffer, 4. barrier
        if (t + 1 < NTl) {
            const int nxt = cur ^ 1;
            #pragma unroll
            for (int i = 0; i < 4; ++i) {
                int p = i * 512 + tid;
                int tn = p >> 10, q = p & 1023, col = q >> 3, d = q & 7;
                *(h16x8*)&smem[nxt][tn][d][col ^ d][0] = stg[i];
            }
        }
        __syncthreads();
    }

    // ---- epilogue: per-lane dims complete; no cross-lane reduce needed ----
    const float inv = 1.0f / s;
    float* orow = out + (((size_t)b * Mc + row) << 6) + ln * 8;
    *(f32x4*)orow       = f32x4{acc8[0]*inv, acc8[1]*inv, acc8[2]*inv, acc8[3]*inv};
    *((f32x4*)orow + 1) = f32x4{acc8[4]*inv, acc8[5]*inv, acc8[6]*inv, acc8[7]*inv};
}

extern "C" void kernel_launch(void* const* d_in, const int* in_sizes, int n_in,
                              void* d_out, int out_size, void* d_ws, size_t ws_size,
                              hipStream_t stream) {
    // inputs: 0 row_indices, 1 row_offsets, 2 column_indices, 3 q3d, 4 k3d, 5 v3d, 6 values
    const int*   cols = (const int*)d_in[2];
    const float* Qm   = (const float*)d_in[3];
    const float* Km   = (const float*)d_in[4];
    const float* Vm   = (const float*)d_in[5];
    float* out = (float*)d_out;

    h16* Kh = (h16*)d_ws;
    h16* Vh = Kh + (size_t)Bc * Nc * Kc;
    h16* Qh = Vh + (size_t)Bc * Nc * Kc;   // 3 x 4.19 MB = 12.6 MB in d_ws

    cvt_fp16<<<dim3(Bc * 3 * 256), dim3(256), 0, stream>>>(
        (const f32x4*)Km, (const f32x4*)Vm, (const f32x4*)Qm,
        (h16x4*)Kh, (h16x4*)Vh, (h16x4*)Qh);

    // 512 blocks = 8 batches x 64 row-blocks (64 rows each); 2 blocks/CU.
    sattn_sweep2<<<dim3(Bc * Mc / 64), dim3(512), 0, stream>>>(
        cols, Qh, Kh, Vh, out);
}